// Round 1
// baseline (1435.409 us; speedup 1.0000x reference)
//
#include <hip/hip_runtime.h>

#define CH    768
#define BC    96
#define HHH   128
#define WWW   128
#define WF    65
#define LAMBD_ 0.01f

// ---------- compile-time twiddle table: c[k]=cos(2*pi*k/128), s[k]=sin(2*pi*k/128)
struct Tab {
  float c[64]; float s[64];
  static constexpr double tsin(double x) {
    double t = x, r = x; const double x2 = x * x;
    for (int i = 1; i <= 15; ++i) { t *= -x2 / ((2.0 * i) * (2.0 * i + 1.0)); r += t; }
    return r;
  }
  static constexpr double tcos(double x) {
    double t = 1.0, r = 1.0; const double x2 = x * x;
    for (int i = 1; i <= 15; ++i) { t *= -x2 / ((2.0 * i - 1.0) * (2.0 * i)); r += t; }
    return r;
  }
  constexpr Tab() : c{}, s{} {
    for (int k = 0; k < 64; ++k) {
      const double a = 6.283185307179586476925287 * (double)k / 128.0;
      c[k] = (float)tcos(a); s[k] = (float)tsin(a);
    }
  }
};
__device__ const Tab DTAB{};   // constant-initialized; const-indexed uses fold to literals

__host__ __device__ constexpr int rev6(int n) {
  int r = 0;
  for (int b = 0; b < 6; ++b) r |= ((n >> b) & 1) << (5 - b);
  return r;
}

// ---------- fully-unrolled in-place DIT FFT-64 on registers (input bit-reversed, output natural)
template<bool INV>
__device__ __forceinline__ void fft64_reg(float (&zr)[64], float (&zi)[64]) {
#pragma unroll
  for (int s = 1; s <= 6; ++s) {
    const int half = 1 << (s - 1);
#pragma unroll
    for (int i = 0; i < 64; i += (1 << s)) {
#pragma unroll
      for (int j = 0; j < half; ++j) {
        const int tw = j << (7 - s);              // index into W_128 table
        const float wr = DTAB.c[tw];
        const float wi = INV ? DTAB.s[tw] : -DTAB.s[tw];
        const int i0 = i + j, i1 = i0 + half;
        const float xr = zr[i1], xi = zi[i1];
        const float vr = xr * wr - xi * wi;
        const float vi = xr * wi + xi * wr;
        const float ur = zr[i0], ui = zi[i0];
        zr[i0] = ur + vr; zi[i0] = ui + vi;
        zr[i1] = ur - vr; zi[i1] = ui - vi;
      }
    }
  }
}

// ---------- K1: rfft along W (packed even/odd trick), scale 1/128, write float2 spectrum
__global__ __launch_bounds__(256, 1) void k_rfft_w(const float* __restrict__ x,
                                                   float2* __restrict__ S) {
  const int idx = blockIdx.x * 256 + threadIdx.x;
  const int c  = idx % CH;
  const int bh = idx / CH;                       // 0..511
  const float* px = x + (size_t)bh * (WWW * CH) + c;
  float zr[64], zi[64];
#pragma unroll
  for (int n = 0; n < 64; ++n) {
    zr[rev6(n)] = px[(size_t)(2 * n) * CH];
    zi[rev6(n)] = px[(size_t)(2 * n + 1) * CH];
  }
  fft64_reg<false>(zr, zi);
  float2* pS = S + (size_t)bh * (WF * CH) + c;
  const float sc = 1.0f / 128.0f;
#pragma unroll
  for (int k = 0; k <= 32; ++k) {
    const int m = (64 - k) & 63;
    const float ar = zr[k], ai = zi[k];
    const float br = zr[m], bi = zi[m];
    const float Er = 0.5f * (ar + br), Ei = 0.5f * (ai - bi);
    const float Or = 0.5f * (ai + bi), Oi = 0.5f * (br - ar);
    const float wr = DTAB.c[k], wi = -DTAB.s[k];   // W_128^k (forward)
    const float Tr = Or * wr - Oi * wi;
    const float Ti = Or * wi + Oi * wr;
    pS[(size_t)k * CH] = make_float2(sc * (Er + Tr), sc * (Ei + Ti));
    if (k != 32)  // X[64-k] = conj(E - T); k=0 writes the Nyquist bin 64
      pS[(size_t)(64 - k) * CH] = make_float2(sc * (Er - Tr), sc * (Ti - Ei));
  }
}

// ---------- K2/K4: in-place complex FFT-128 along H in LDS. One WG = (b, wf, 32-ch tile)
template<bool INV>
__global__ __launch_bounds__(256) void k_fft_h(float2* __restrict__ S) {
  __shared__ float lr[128 * 33];
  __shared__ float li[128 * 33];
  const int tid = threadIdx.x;
  const int c = tid & 31;
  const int g = tid >> 5;                         // 0..7
  const int ct = blockIdx.x % 24;
  const int t2 = blockIdx.x / 24;
  const int wf = t2 % WF;
  const int b  = t2 / WF;
  float2* base = S + ((size_t)(b * HHH) * WF + wf) * CH + ct * 32 + c;
  const size_t hs = (size_t)WF * CH;              // float2 stride between h rows
#pragma unroll
  for (int t = 0; t < 16; ++t) {
    const int h = t * 8 + g;
    const float2 v = base[(size_t)h * hs];
    const int hb = (int)(__brev((unsigned)h) >> 25);  // 7-bit reverse
    lr[hb * 33 + c] = v.x;
    li[hb * 33 + c] = v.y;
  }
  __syncthreads();
#pragma unroll
  for (int s = 1; s <= 7; ++s) {
    const int half = 1 << (s - 1);
#pragma unroll
    for (int t = 0; t < 8; ++t) {
      const int bf = g * 8 + t;
      const int j  = bf & (half - 1);
      const int i0 = ((bf >> (s - 1)) << s) + j;
      const int i1 = i0 + half;
      const int tw = j << (7 - s);
      const float wr = DTAB.c[tw];
      const float wi = INV ? DTAB.s[tw] : -DTAB.s[tw];
      const float ur = lr[i0 * 33 + c], ui = li[i0 * 33 + c];
      const float xr = lr[i1 * 33 + c], xi = li[i1 * 33 + c];
      const float vr = xr * wr - xi * wi;
      const float vi = xr * wi + xi * wr;
      lr[i0 * 33 + c] = ur + vr;  li[i0 * 33 + c] = ui + vi;
      lr[i1 * 33 + c] = ur - vr;  li[i1 * 33 + c] = ui - vi;
    }
    __syncthreads();
  }
#pragma unroll
  for (int t = 0; t < 16; ++t) {
    const int h = t * 8 + g;
    base[(size_t)h * hs] = make_float2(lr[h * 33 + c], li[h * 33 + c]);
  }
}

// ---------- K3: per-mode block-diagonal complex MLP (f32), in-place on S
__global__ __launch_bounds__(256) void k_mlp(float2* __restrict__ S,
                                             const float* __restrict__ w1,
                                             const float* __restrict__ b1,
                                             const float* __restrict__ w2,
                                             const float* __restrict__ b2) {
  __shared__ float Xr[32][BC], Xi[32][BC];
  __shared__ float Qr[32][BC], Qi[32][BC];
  const int n  = blockIdx.x & 7;
  const int p0 = (blockIdx.x >> 3) * 32;
  const int tid = threadIdx.x;
  float2* base = S + (size_t)p0 * CH + n * BC;
#pragma unroll
  for (int i = 0; i < 12; ++i) {
    const int q = tid + i * 256;                  // 0..3071
    const int p = q / BC, ch = q - p * BC;
    const float2 v = base[(size_t)p * CH + ch];
    Xr[p][ch] = v.x; Xi[p][ch] = v.y;
  }
  __syncthreads();
  const int og = tid & 15, pg = tid >> 4;
  const int o0 = og * 6, pA = pg * 2, pB = pA + 1;
  float ar0[6], ai0[6], ar1[6], ai1[6];
  // ----- layer 1
  {
    const float* w_r = w1 + (size_t)n * (BC * BC);
    const float* w_i = w1 + (size_t)(8 + n) * (BC * BC);
    const float* pbr = b1 + n * BC + o0;
    const float* pbi = b1 + (8 + n) * BC + o0;
#pragma unroll
    for (int j = 0; j < 6; ++j) { ar0[j] = pbr[j]; ar1[j] = pbr[j]; ai0[j] = pbi[j]; ai1[j] = pbi[j]; }
#pragma unroll 4
    for (int k = 0; k < BC; ++k) {
      const float xr0 = Xr[pA][k], xi0 = Xi[pA][k];
      const float xr1 = Xr[pB][k], xi1 = Xi[pB][k];
      const float* wr_ = w_r + k * BC + o0;
      const float* wi_ = w_i + k * BC + o0;
#pragma unroll
      for (int j = 0; j < 6; ++j) {
        const float wr = wr_[j], wi = wi_[j];
        ar0[j] = fmaf(xr0, wr, ar0[j]); ar0[j] = fmaf(-xi0, wi, ar0[j]);
        ai0[j] = fmaf(xi0, wr, ai0[j]); ai0[j] = fmaf(xr0, wi, ai0[j]);
        ar1[j] = fmaf(xr1, wr, ar1[j]); ar1[j] = fmaf(-xi1, wi, ar1[j]);
        ai1[j] = fmaf(xi1, wr, ai1[j]); ai1[j] = fmaf(xr1, wi, ai1[j]);
      }
    }
#pragma unroll
    for (int j = 0; j < 6; ++j) {
      Qr[pA][o0 + j] = fmaxf(ar0[j], 0.f);
      Qi[pA][o0 + j] = fmaxf(ai0[j], 0.f);
      Qr[pB][o0 + j] = fmaxf(ar1[j], 0.f);
      Qi[pB][o0 + j] = fmaxf(ai1[j], 0.f);
    }
  }
  __syncthreads();
  // ----- layer 2 + softshrink
  {
    const float* w_r = w2 + (size_t)n * (BC * BC);
    const float* w_i = w2 + (size_t)(8 + n) * (BC * BC);
    const float* pbr = b2 + n * BC + o0;
    const float* pbi = b2 + (8 + n) * BC + o0;
#pragma unroll
    for (int j = 0; j < 6; ++j) { ar0[j] = pbr[j]; ar1[j] = pbr[j]; ai0[j] = pbi[j]; ai1[j] = pbi[j]; }
#pragma unroll 4
    for (int k = 0; k < BC; ++k) {
      const float xr0 = Qr[pA][k], xi0 = Qi[pA][k];
      const float xr1 = Qr[pB][k], xi1 = Qi[pB][k];
      const float* wr_ = w_r + k * BC + o0;
      const float* wi_ = w_i + k * BC + o0;
#pragma unroll
      for (int j = 0; j < 6; ++j) {
        const float wr = wr_[j], wi = wi_[j];
        ar0[j] = fmaf(xr0, wr, ar0[j]); ar0[j] = fmaf(-xi0, wi, ar0[j]);
        ai0[j] = fmaf(xi0, wr, ai0[j]); ai0[j] = fmaf(xr0, wi, ai0[j]);
        ar1[j] = fmaf(xr1, wr, ar1[j]); ar1[j] = fmaf(-xi1, wi, ar1[j]);
        ai1[j] = fmaf(xi1, wr, ai1[j]); ai1[j] = fmaf(xr1, wi, ai1[j]);
      }
    }
#pragma unroll
    for (int j = 0; j < 6; ++j) {
      float vr = ar0[j], vi = ai0[j];
      vr = vr > LAMBD_ ? vr - LAMBD_ : (vr < -LAMBD_ ? vr + LAMBD_ : 0.f);
      vi = vi > LAMBD_ ? vi - LAMBD_ : (vi < -LAMBD_ ? vi + LAMBD_ : 0.f);
      base[(size_t)pA * CH + o0 + j] = make_float2(vr, vi);
      float ur = ar1[j], ui = ai1[j];
      ur = ur > LAMBD_ ? ur - LAMBD_ : (ur < -LAMBD_ ? ur + LAMBD_ : 0.f);
      ui = ui > LAMBD_ ? ui - LAMBD_ : (ui < -LAMBD_ ? ui + LAMBD_ : 0.f);
      base[(size_t)pB * CH + o0 + j] = make_float2(ur, ui);
    }
  }
}

// ---------- K5: inverse rfft along W (packed trick), 1/128 scale, + residual
__global__ __launch_bounds__(256, 1) void k_irfft_w(const float2* __restrict__ S,
                                                    const float* __restrict__ x,
                                                    float* __restrict__ out) {
  const int idx = blockIdx.x * 256 + threadIdx.x;
  const int c  = idx % CH;
  const int bh = idx / CH;
  const float2* pS = S + (size_t)bh * (WF * CH) + c;
  float zr[64], zi[64];
#pragma unroll
  for (int k = 0; k <= 32; ++k) {
    float2 Yk = pS[(size_t)k * CH];
    float2 Ym = pS[(size_t)(64 - k) * CH];
    if (k == 0) { Yk.y = 0.f; Ym.y = 0.f; }       // c2r ignores imag of DC & Nyquist
    const float er = Yk.x + Ym.x, ei = Yk.y - Ym.y;
    const float dr = Yk.x - Ym.x, di = Yk.y + Ym.y;
    const float wr = DTAB.c[k], wi = DTAB.s[k];   // e^{+2pi i k/128}
    const float o_r = dr * wr - di * wi;
    const float o_i = dr * wi + di * wr;
    zr[rev6(k)] = er - o_i;  zi[rev6(k)] = ei + o_r;
    if (k > 0 && k < 32) {
      zr[rev6(64 - k)] = er + o_i;  zi[rev6(64 - k)] = o_r - ei;
    }
  }
  fft64_reg<true>(zr, zi);
  const float sc = 1.0f / 128.0f;
  const float* px = x + (size_t)bh * (WWW * CH) + c;
  float* po = out + (size_t)bh * (WWW * CH) + c;
#pragma unroll
  for (int n = 0; n < 64; ++n) {
    po[(size_t)(2 * n) * CH]     = fmaf(zr[n], sc, px[(size_t)(2 * n) * CH]);
    po[(size_t)(2 * n + 1) * CH] = fmaf(zi[n], sc, px[(size_t)(2 * n + 1) * CH]);
  }
}

extern "C" void kernel_launch(void* const* d_in, const int* in_sizes, int n_in,
                              void* d_out, int out_size, void* d_ws, size_t ws_size,
                              hipStream_t stream) {
  (void)in_sizes; (void)n_in; (void)out_size; (void)ws_size;
  const float* x  = (const float*)d_in[0];
  const float* w1 = (const float*)d_in[1];
  const float* b1 = (const float*)d_in[2];
  const float* w2 = (const float*)d_in[3];
  const float* b2 = (const float*)d_in[4];
  float* out = (float*)d_out;
  float2* S  = (float2*)d_ws;                     // [B][H][WF][CH] interleaved complex, ~204.5 MB

  k_rfft_w<<<dim3(1536), dim3(256), 0, stream>>>(x, S);
  k_fft_h<false><<<dim3(6240), dim3(256), 0, stream>>>(S);
  k_mlp<<<dim3(1040 * 8), dim3(256), 0, stream>>>(S, w1, b1, w2, b2);
  k_fft_h<true><<<dim3(6240), dim3(256), 0, stream>>>(S);
  k_irfft_w<<<dim3(1536), dim3(256), 0, stream>>>(S, x, out);
}

// Round 3
// 777.812 us; speedup vs baseline: 1.8454x; 1.8454x over previous
//
#include <hip/hip_runtime.h>

#define CH    768
#define BC    96
#define HHH   128
#define WWW   128
#define WF    65
#define LAMBD_ 0.01f
#define NPOS  33280              // B*H*WF = 4*128*65
#define SOFF  204472320ull       // bytes of spectrum S in d_ws

typedef __bf16 bf16x8 __attribute__((ext_vector_type(8)));
typedef float  f32x4  __attribute__((ext_vector_type(4)));
typedef unsigned short ushort_t;

union U8 { ushort_t u[8]; bf16x8 v; uint4 q; };

__device__ __forceinline__ ushort_t rnbf(float f) {   // f32 -> bf16 round-to-nearest-even
  unsigned u = __builtin_bit_cast(unsigned, f);
  return (ushort_t)((u + 0x7FFFu + ((u >> 16) & 1u)) >> 16);
}

// ---------- compile-time twiddle table: c[k]=cos(2*pi*k/128), s[k]=sin(2*pi*k/128)
struct Tab {
  float c[64]; float s[64];
  static constexpr double tsin(double x) {
    double t = x, r = x; const double x2 = x * x;
    for (int i = 1; i <= 15; ++i) { t *= -x2 / ((2.0 * i) * (2.0 * i + 1.0)); r += t; }
    return r;
  }
  static constexpr double tcos(double x) {
    double t = 1.0, r = 1.0; const double x2 = x * x;
    for (int i = 1; i <= 15; ++i) { t *= -x2 / ((2.0 * i - 1.0) * (2.0 * i)); r += t; }
    return r;
  }
  constexpr Tab() : c{}, s{} {
    for (int k = 0; k < 64; ++k) {
      const double a = 6.283185307179586476925287 * (double)k / 128.0;
      c[k] = (float)tcos(a); s[k] = (float)tsin(a);
    }
  }
};
__device__ const Tab DTAB{};

__host__ __device__ constexpr int rev6(int n) {
  int r = 0;
  for (int b = 0; b < 6; ++b) r |= ((n >> b) & 1) << (5 - b);
  return r;
}

// ---------- fully-unrolled in-place DIT FFT-64 on registers
template<bool INV>
__device__ __forceinline__ void fft64_reg(float (&zr)[64], float (&zi)[64]) {
#pragma unroll
  for (int s = 1; s <= 6; ++s) {
    const int half = 1 << (s - 1);
#pragma unroll
    for (int i = 0; i < 64; i += (1 << s)) {
#pragma unroll
      for (int j = 0; j < half; ++j) {
        const int tw = j << (7 - s);
        const float wr = DTAB.c[tw];
        const float wi = INV ? DTAB.s[tw] : -DTAB.s[tw];
        const int i0 = i + j, i1 = i0 + half;
        const float xr = zr[i1], xi = zi[i1];
        const float vr = xr * wr - xi * wi;
        const float vi = xr * wi + xi * wr;
        const float ur = zr[i0], ui = zi[i0];
        zr[i0] = ur + vr; zi[i0] = ui + vi;
        zr[i1] = ur - vr; zi[i1] = ui - vi;
      }
    }
  }
}

// ---------- K1: rfft along W (packed even/odd trick), scale 1/128
__global__ __launch_bounds__(256, 1) void k_rfft_w(const float* __restrict__ x,
                                                   float2* __restrict__ S) {
  const int idx = blockIdx.x * 256 + threadIdx.x;
  const int c  = idx % CH;
  const int bh = idx / CH;
  const float* px = x + (size_t)bh * (WWW * CH) + c;
  float zr[64], zi[64];
#pragma unroll
  for (int n = 0; n < 64; ++n) {
    zr[rev6(n)] = px[(size_t)(2 * n) * CH];
    zi[rev6(n)] = px[(size_t)(2 * n + 1) * CH];
  }
  fft64_reg<false>(zr, zi);
  float2* pS = S + (size_t)bh * (WF * CH) + c;
  const float sc = 1.0f / 128.0f;
#pragma unroll
  for (int k = 0; k <= 32; ++k) {
    const int m = (64 - k) & 63;
    const float ar = zr[k], ai = zi[k];
    const float br = zr[m], bi = zi[m];
    const float Er = 0.5f * (ar + br), Ei = 0.5f * (ai - bi);
    const float Or = 0.5f * (ai + bi), Oi = 0.5f * (br - ar);
    const float wr = DTAB.c[k], wi = -DTAB.s[k];
    const float Tr = Or * wr - Oi * wi;
    const float Ti = Or * wi + Oi * wr;
    pS[(size_t)k * CH] = make_float2(sc * (Er + Tr), sc * (Ei + Ti));
    if (k != 32)
      pS[(size_t)(64 - k) * CH] = make_float2(sc * (Er - Tr), sc * (Ti - Ei));
  }
}

// ---------- K2/K4: in-place complex FFT-128 along H in LDS
template<bool INV>
__global__ __launch_bounds__(256) void k_fft_h(float2* __restrict__ S) {
  __shared__ float lr[128 * 33];
  __shared__ float li[128 * 33];
  const int tid = threadIdx.x;
  const int c = tid & 31;
  const int g = tid >> 5;
  const int ct = blockIdx.x % 24;
  const int t2 = blockIdx.x / 24;
  const int wf = t2 % WF;
  const int b  = t2 / WF;
  float2* base = S + ((size_t)(b * HHH) * WF + wf) * CH + ct * 32 + c;
  const size_t hs = (size_t)WF * CH;
#pragma unroll
  for (int t = 0; t < 16; ++t) {
    const int h = t * 8 + g;
    const float2 v = base[(size_t)h * hs];
    const int hb = (int)(__brev((unsigned)h) >> 25);
    lr[hb * 33 + c] = v.x;
    li[hb * 33 + c] = v.y;
  }
  __syncthreads();
#pragma unroll
  for (int s = 1; s <= 7; ++s) {
    const int half = 1 << (s - 1);
#pragma unroll
    for (int t = 0; t < 8; ++t) {
      const int bf = g * 8 + t;
      const int j  = bf & (half - 1);
      const int i0 = ((bf >> (s - 1)) << s) + j;
      const int i1 = i0 + half;
      const int tw = j << (7 - s);
      const float wr = DTAB.c[tw];
      const float wi = INV ? DTAB.s[tw] : -DTAB.s[tw];
      const float ur = lr[i0 * 33 + c], ui = li[i0 * 33 + c];
      const float xr = lr[i1 * 33 + c], xi = li[i1 * 33 + c];
      const float vr = xr * wr - xi * wi;
      const float vi = xr * wi + xi * wr;
      lr[i0 * 33 + c] = ur + vr;  li[i0 * 33 + c] = ui + vi;
      lr[i1 * 33 + c] = ur - vr;  li[i1 * 33 + c] = ui - vi;
    }
    __syncthreads();
  }
#pragma unroll
  for (int t = 0; t < 16; ++t) {
    const int h = t * 8 + g;
    base[(size_t)h * hs] = make_float2(lr[h * 33 + c], li[h * 33 + c]);
  }
}

// ---------- weight pre-pack: combined complex-as-real 192x192 per (block, layer),
// bf16, stored in MFMA-fragment order [n][layer][ki][ni][lane][j]
__global__ __launch_bounds__(256) void k_pack(const float* __restrict__ w1,
                                              const float* __restrict__ w2,
                                              ushort_t* __restrict__ Bpk) {
  const int t = blockIdx.x * 256 + threadIdx.x;       // < 1179648/2
  const int nl   = t / 36864;
  const int rem  = t % 36864;
  const int ki   = rem / 6144;
  const int rem2 = rem % 6144;
  const int ni   = rem2 / 512;
  const int rem3 = rem2 % 512;
  const int lane = rem3 >> 3, j = rem3 & 7;
  const int n = nl >> 1, layer = nl & 1;
  const int k   = ki * 32 + (lane >> 4) * 8 + j;
  const int col = ni * 16 + (lane & 15);
  const int kk = (k < 96) ? k : k - 96;
  const int cc = (col < 96) ? col : col - 96;
  const int f  = ((k < 96) != (col < 96)) ? 1 : 0;    // off-diagonal blocks = imag part
  const float sgn = (k >= 96 && col < 96) ? -1.f : 1.f;
  const float* w = layer ? w2 : w1;
  const float val = sgn * w[((size_t)(f * 8 + n) * 96 + kk) * 96 + cc];
  Bpk[t] = rnbf(val);
}

// ---------- K3: MFMA block-MLP, in-place on S. WG = 4 waves; wave = 16 pos x N=192.
__global__ __launch_bounds__(256) void k_mlp2(float2* __restrict__ S,
                                              const ushort_t* __restrict__ Bpk,
                                              const float* __restrict__ b1,
                                              const float* __restrict__ b2) {
  __shared__ ushort_t o1[64 * 200];                   // 4 wave tiles, 200-padded rows
  const int tid = threadIdx.x;
  const int l = tid & 63, wid = tid >> 6;
  const int lr = l & 15, lg = l >> 4;                 // A-row-in-tile / k-group
  const int n  = blockIdx.x & 7;
  const int p0 = (blockIdx.x >> 3) * 64 + wid * 16;   // wave's first position

  // ----- A1 fragments: X = [Xr | Xi], straight from global (f32 -> bf16)
  U8 aR[3], aI[3];
  const float4* xbase = (const float4*)(S + (size_t)(p0 + lr) * CH + n * BC);
#pragma unroll
  for (int kp = 0; kp < 3; ++kp) {
    const float4* q = xbase + (kp * 32 + lg * 8) / 2; // 8 float2 = 4 float4
    const float4 f0 = q[0], f1 = q[1], f2 = q[2], f3 = q[3];
    aR[kp].u[0] = rnbf(f0.x); aR[kp].u[1] = rnbf(f0.z);
    aR[kp].u[2] = rnbf(f1.x); aR[kp].u[3] = rnbf(f1.z);
    aR[kp].u[4] = rnbf(f2.x); aR[kp].u[5] = rnbf(f2.z);
    aR[kp].u[6] = rnbf(f3.x); aR[kp].u[7] = rnbf(f3.z);
    aI[kp].u[0] = rnbf(f0.y); aI[kp].u[1] = rnbf(f0.w);
    aI[kp].u[2] = rnbf(f1.y); aI[kp].u[3] = rnbf(f1.w);
    aI[kp].u[4] = rnbf(f2.y); aI[kp].u[5] = rnbf(f2.w);
    aI[kp].u[6] = rnbf(f3.y); aI[kp].u[7] = rnbf(f3.w);
  }

  f32x4 acc[12];
  // ----- layer 1: acc = X * B1 + b1
#pragma unroll
  for (int ni = 0; ni < 12; ++ni) {
    const int col = ni * 16 + lr;
    const float bv = (col < 96) ? b1[n * 96 + col] : b1[768 + n * 96 + col - 96];
    acc[ni] = (f32x4){bv, bv, bv, bv};
  }
  const uint4* bq1 = (const uint4*)(Bpk + (size_t)(n * 2 + 0) * 36864) + l;
#pragma unroll
  for (int ni = 0; ni < 12; ++ni)
#pragma unroll
    for (int ki = 0; ki < 6; ++ki) {
      U8 b; b.q = bq1[(ki * 12 + ni) * 64];
      const bf16x8 a = (ki < 3) ? aR[ki].v : aI[ki - 3].v;
      acc[ni] = __builtin_amdgcn_mfma_f32_16x16x32_bf16(a, b.v, acc[ni], 0, 0, 0);
    }
  // relu -> bf16 -> LDS (row-padded to 200 ushorts = 400 B)
#pragma unroll
  for (int ni = 0; ni < 12; ++ni) {
    const int col = ni * 16 + lr;
#pragma unroll
    for (int r = 0; r < 4; ++r) {
      const int grow = wid * 16 + lg * 4 + r;
      o1[grow * 200 + col] = rnbf(fmaxf(acc[ni][r], 0.f));
    }
  }
  __syncthreads();

  // ----- layer 2: A2 fragments from LDS
  U8 a2[6];
#pragma unroll
  for (int ki = 0; ki < 6; ++ki)
    a2[ki].q = *(const uint4*)&o1[(wid * 16 + lr) * 200 + ki * 32 + lg * 8];
#pragma unroll
  for (int ni = 0; ni < 12; ++ni) {
    const int col = ni * 16 + lr;
    const float bv = (col < 96) ? b2[n * 96 + col] : b2[768 + n * 96 + col - 96];
    acc[ni] = (f32x4){bv, bv, bv, bv};
  }
  const uint4* bq2 = (const uint4*)(Bpk + (size_t)(n * 2 + 1) * 36864) + l;
#pragma unroll
  for (int ni = 0; ni < 12; ++ni)
#pragma unroll
    for (int ki = 0; ki < 6; ++ki) {
      U8 b; b.q = bq2[(ki * 12 + ni) * 64];
      acc[ni] = __builtin_amdgcn_mfma_f32_16x16x32_bf16(a2[ki].v, b.v, acc[ni], 0, 0, 0);
    }
  // softshrink, scatter back in-place (real / imag halves)
  float* Sf = (float*)S;
#pragma unroll
  for (int ni = 0; ni < 12; ++ni) {
    const int col = ni * 16 + lr;
    const int c    = (col < 96) ? col : col - 96;
    const int comp = (col < 96) ? 0 : 1;
#pragma unroll
    for (int r = 0; r < 4; ++r) {
      const int p = p0 + lg * 4 + r;
      float v = acc[ni][r];
      v = v > LAMBD_ ? v - LAMBD_ : (v < -LAMBD_ ? v + LAMBD_ : 0.f);
      Sf[2 * ((size_t)p * CH + n * BC + c) + comp] = v;
    }
  }
}

// ---------- K5: inverse rfft along W + residual
__global__ __launch_bounds__(256, 1) void k_irfft_w(const float2* __restrict__ S,
                                                    const float* __restrict__ x,
                                                    float* __restrict__ out) {
  const int idx = blockIdx.x * 256 + threadIdx.x;
  const int c  = idx % CH;
  const int bh = idx / CH;
  const float2* pS = S + (size_t)bh * (WF * CH) + c;
  float zr[64], zi[64];
#pragma unroll
  for (int k = 0; k <= 32; ++k) {
    float2 Yk = pS[(size_t)k * CH];
    float2 Ym = pS[(size_t)(64 - k) * CH];
    if (k == 0) { Yk.y = 0.f; Ym.y = 0.f; }
    const float er = Yk.x + Ym.x, ei = Yk.y - Ym.y;
    const float dr = Yk.x - Ym.x, di = Yk.y + Ym.y;
    const float wr = DTAB.c[k], wi = DTAB.s[k];
    const float o_r = dr * wr - di * wi;
    const float o_i = dr * wi + di * wr;
    zr[rev6(k)] = er - o_i;  zi[rev6(k)] = ei + o_r;
    if (k > 0 && k < 32) {
      zr[rev6(64 - k)] = er + o_i;  zi[rev6(64 - k)] = o_r - ei;
    }
  }
  fft64_reg<true>(zr, zi);
  const float sc = 1.0f / 128.0f;
  const float* px = x + (size_t)bh * (WWW * CH) + c;
  float* po = out + (size_t)bh * (WWW * CH) + c;
#pragma unroll
  for (int n = 0; n < 64; ++n) {
    po[(size_t)(2 * n) * CH]     = fmaf(zr[n], sc, px[(size_t)(2 * n) * CH]);
    po[(size_t)(2 * n + 1) * CH] = fmaf(zi[n], sc, px[(size_t)(2 * n + 1) * CH]);
  }
}

extern "C" void kernel_launch(void* const* d_in, const int* in_sizes, int n_in,
                              void* d_out, int out_size, void* d_ws, size_t ws_size,
                              hipStream_t stream) {
  (void)in_sizes; (void)n_in; (void)out_size; (void)ws_size;
  const float* x  = (const float*)d_in[0];
  const float* w1 = (const float*)d_in[1];
  const float* b1 = (const float*)d_in[2];
  const float* w2 = (const float*)d_in[3];
  const float* b2 = (const float*)d_in[4];
  float* out = (float*)d_out;
  float2* S  = (float2*)d_ws;                           // spectrum, 204.5 MB
  ushort_t* Bpk = (ushort_t*)((char*)d_ws + SOFF);      // packed bf16 weights, 1.13 MB

  k_pack<<<dim3(2304), dim3(256), 0, stream>>>(w1, w2, Bpk);
  k_rfft_w<<<dim3(1536), dim3(256), 0, stream>>>(x, S);
  k_fft_h<false><<<dim3(6240), dim3(256), 0, stream>>>(S);
  k_mlp2<<<dim3((NPOS / 64) * 8), dim3(256), 0, stream>>>(S, Bpk, b1, b2);
  k_fft_h<true><<<dim3(6240), dim3(256), 0, stream>>>(S);
  k_irfft_w<<<dim3(1536), dim3(256), 0, stream>>>(S, x, out);
}